// Round 3
// baseline (3732.920 us; speedup 1.0000x reference)
//
#include <hip/hip_runtime.h>

// 3-layer LSTM, B=256, T=2048, H=128 — v3: seq-batched MFMA + layer-per-block
// cross-CU chunk pipeline.
// R2 post-mortem: broadcast-A MFMA wastes 15/16 of the matrix pipe and the
// 192-VGPR weight file was demoted to AGPRs (VGPR_Count=128 => v_accvgpr_read
// shuttle = the 30% VALUBusy). v3 restructures:
//  - 48 blocks = 16 seq-groups x 3 layers. Block (L,g): layer L, seqs 16g..16g+15.
//  - Recurrent GEMM batched over 16 seqs: A rows = seqs -> FULL MFMA util.
//    Per wave: 4 gate-tiles x (4 proj + 4 rec chained) = 32 MFMAs/step.
//  - Wave j owns units [16j,16j+16) for ALL 4 gates -> i,f,g,o in-register per
//    lane (seq=4p+r, unit=16j+c). No shuffles, no xg_s.
//  - Layer L consumes layer L-1's h chunk (16 steps) via global hbuf + agent-
//    scope release/acquire flags. h1 overwrites h0 slot in place (single
//    producer->consumer per slot). Layer0 blocks first in bid order => DAG
//    completes even under serialized dispatch (G16-safe).
//  - LDS h slices swizzled (u ^= 8*(seq&7)): A-frag ds_read_b128 and h
//    ds_write_u16 both <=2-way banked.
// Watch: VGPR_Count ~200-240 (128 => AGPR demotion again; 256 => spill),
// bank conflicts <2e7, hang => flag bug.

#define HDIM 128
#define TDIM 2048
#define NB 16       // sequences per group (MFMA rows)
#define NG 16       // groups
#define CH 16       // chunk length (timesteps)
#define NCH 128     // chunks per sequence
#define NT 512      // 8 waves

typedef _Float16 half8_t __attribute__((ext_vector_type(8)));
typedef float f32x4 __attribute__((ext_vector_type(4)));

__device__ __forceinline__ f32x4 mfma16(half8_t a, half8_t b, f32x4 c) {
    return __builtin_amdgcn_mfma_f32_16x16x32_f16(a, b, c, 0, 0, 0);
}

// Workgroup barrier WITHOUT vmcnt(0) drain: LDS visibility only.
__device__ __forceinline__ void fast_barrier() {
    asm volatile("s_waitcnt lgkmcnt(0)\n\ts_barrier" ::: "memory");
}

__device__ __forceinline__ float sigm_f(float x) {
    return __builtin_amdgcn_rcpf(1.0f + __expf(-x));
}
__device__ __forceinline__ float tanh_f(float x) {
    return fmaf(-2.0f, __builtin_amdgcn_rcpf(1.0f + __expf(2.0f * x)), 1.0f);
}

// One-time fp32 -> fp16 weight conversion + flag zeroing.
// Segments of 65536: [Whh0,Wih1,Whh1,Wih2,Whh2]
__global__ __launch_bounds__(256)
void convert_w(const float* __restrict__ Whh0, const float* __restrict__ Wih1,
               const float* __restrict__ Whh1, const float* __restrict__ Wih2,
               const float* __restrict__ Whh2, _Float16* __restrict__ dst,
               int* __restrict__ flags) {
    int i = blockIdx.x * 256 + threadIdx.x;
    if (i < 2 * NG * NCH) flags[i] = 0;
    int seg = i >> 16, off = i & 65535;
    const float* s = (seg == 0) ? Whh0 : (seg == 1) ? Wih1 : (seg == 2) ? Whh1
                   : (seg == 3) ? Wih2 : Whh2;
    dst[i] = (_Float16)s[off];
}

__global__ __launch_bounds__(NT, 2)
void lstm3_pipe(const float* __restrict__ x,   const float* __restrict__ Wih0,
                const float* __restrict__ bih0, const float* __restrict__ bhh0,
                const float* __restrict__ bih1, const float* __restrict__ bhh1,
                const float* __restrict__ bih2, const float* __restrict__ bhh2,
                const float* __restrict__ fc1w, const float* __restrict__ fc1b,
                const float* __restrict__ fc2w, const float* __restrict__ fc2b,
                float* __restrict__ out,
                _Float16* __restrict__ hbuf, const _Float16* __restrict__ wbuf,
                int* __restrict__ flags)
{
    // own h window (one chunk, swizzled slices) + staged prev-layer chunk
    __shared__ __align__(16) _Float16 hown[CH * NB * HDIM];  // 64 KB
    __shared__ __align__(16) _Float16 hst [CH * NB * HDIM];  // 64 KB
    __shared__ float x_s[CH][NB];                            // layer0 input
    __shared__ float z_s[NB][64];                            // FC tail
    __shared__ float hfin[NB][HDIM];                         // de-swizzled hT

    const int tid = threadIdx.x;
    const int ln = tid & 63, wv = tid >> 6;   // wave j owns units [16j,16j+16)
    const int c = ln & 15, p = ln >> 4;       // col-in-tile / row-quadrant
    const int L = blockIdx.x >> 4;            // layer 0..2 (layer0 = bids 0..15)
    const int g = blockIdx.x & 15;            // seq group

    // ---- resident weight fragments: B[k][n] -> lane(c=n, p): W[row][m*32+p*8+e]
    const _Float16* whh = wbuf + (size_t)((L == 0) ? 0 : (L == 1) ? 2 : 4) * 65536;
    const _Float16* wih = wbuf + (size_t)((L == 1) ? 1 : 3) * 65536;  // L0: unused
    half8_t whh_f[4][4], wih_f[4][4];
#pragma unroll
    for (int q = 0; q < 4; ++q)
#pragma unroll
        for (int m = 0; m < 4; ++m) {
            whh_f[q][m] = *(const half8_t*)(whh + (size_t)(q*HDIM + wv*16 + c)*HDIM + m*32 + p*8);
            if (L > 0)
                wih_f[q][m] = *(const half8_t*)(wih + (size_t)(q*HDIM + wv*16 + c)*HDIM + m*32 + p*8);
        }

    const float* bihL = (L == 0) ? bih0 : (L == 1) ? bih1 : bih2;
    const float* bhhL = (L == 0) ? bhh0 : (L == 1) ? bhh1 : bhh2;
    const int u = wv * 16 + c;                // this lane's unit
    float bias[4], w0[4];
#pragma unroll
    for (int q = 0; q < 4; ++q) {
        bias[q] = bihL[q*HDIM + u] + bhhL[q*HDIM + u];
        w0[q] = (L == 0) ? Wih0[q*HDIM + u] : 0.0f;
    }

    // swizzled offsets: slice layout [seq][u ^ 8*(seq&7)]
    int roff[4], woff[4];
#pragma unroll
    for (int m = 0; m < 4; ++m)
        roff[m] = c*HDIM + ((32*m + 8*p) ^ (8*(c & 7)));
#pragma unroll
    for (int r = 0; r < 4; ++r) {
        int seq = p*4 + r;
        woff[r] = seq*HDIM + (u ^ (8*(seq & 7)));
    }

    // h(-1) = 0: zero slice 15 (read as "prev" at chunk 0, step 0)
    for (int i = tid; i < NB*HDIM/2; i += NT)
        ((int*)(hown + 15*NB*HDIM))[i] = 0;
    float cc[4] = {0.f, 0.f, 0.f, 0.f};
    __syncthreads();

    int* fprod = flags + (L*NG + g)*NCH;          // set by this block (L<2)
    int* fcons = flags + ((L-1)*NG + g)*NCH;      // waited on (L>0)
    const float* xb = x + (size_t)(g*NB)*TDIM;

#pragma unroll 1
    for (int s = 0; s < NCH; ++s) {
        _Float16* gch = hbuf + ((size_t)(g*NCH + s) << 15);   // 64 KB slot

        if (L == 0) {
            if (tid < CH*NB)
                x_s[tid >> 4][tid & 15] = xb[(size_t)(tid & 15)*TDIM + s*CH + (tid >> 4)];
        } else {
            // wait for producer chunk, then stage it (acquire inv covers CU L1 + XCD L2)
            if (tid == 0) {
                while (__hip_atomic_load(fcons + s, __ATOMIC_ACQUIRE,
                                         __HIP_MEMORY_SCOPE_AGENT) == 0)
                    __builtin_amdgcn_s_sleep(8);
            }
            __syncthreads();
            const float4* gsrc = (const float4*)gch;
            float4* dv = (float4*)hst;
#pragma unroll
            for (int k2 = 0; k2 < 8; ++k2) dv[k2*NT + tid] = gsrc[k2*NT + tid];
        }
        fast_barrier();   // staging visible

#pragma unroll 1
        for (int tt = 0; tt < CH; ++tt) {
            const int tp = (tt + CH - 1) & 15;
            const _Float16* rsl = hown + tp*(NB*HDIM);
            const _Float16* psl = hst  + tt*(NB*HDIM);
            // rec A-frags: A[row=seq=c][k = m*32+p*8+e] from swizzled slice
            half8_t A0 = *(const half8_t*)(rsl + roff[0]);
            half8_t A1 = *(const half8_t*)(rsl + roff[1]);
            half8_t A2 = *(const half8_t*)(rsl + roff[2]);
            half8_t A3 = *(const half8_t*)(rsl + roff[3]);

            f32x4 acc[4];
            if (L > 0) {
                half8_t P0 = *(const half8_t*)(psl + roff[0]);
                half8_t P1 = *(const half8_t*)(psl + roff[1]);
                half8_t P2 = *(const half8_t*)(psl + roff[2]);
                half8_t P3 = *(const half8_t*)(psl + roff[3]);
#pragma unroll
                for (int q = 0; q < 4; ++q) {
                    f32x4 a = {0.f, 0.f, 0.f, 0.f};
                    a = mfma16(P0, wih_f[q][0], a);
                    a = mfma16(P1, wih_f[q][1], a);
                    a = mfma16(P2, wih_f[q][2], a);
                    a = mfma16(P3, wih_f[q][3], a);
                    acc[q] = a;
                }
            } else {
#pragma unroll
                for (int q = 0; q < 4; ++q) acc[q] = (f32x4){0.f, 0.f, 0.f, 0.f};
            }
#pragma unroll
            for (int q = 0; q < 4; ++q) {
                acc[q] = mfma16(A0, whh_f[q][0], acc[q]);
                acc[q] = mfma16(A1, whh_f[q][1], acc[q]);
                acc[q] = mfma16(A2, whh_f[q][2], acc[q]);
                acc[q] = mfma16(A3, whh_f[q][3], acc[q]);
            }

            _Float16* wsl = hown + tt*(NB*HDIM);
#pragma unroll
            for (int r = 0; r < 4; ++r) {
                float pi = acc[0][r] + bias[0];
                float pf = acc[1][r] + bias[1];
                float pg = acc[2][r] + bias[2];
                float po = acc[3][r] + bias[3];
                if (L == 0) {
                    float xr = x_s[tt][p*4 + r];
                    pi = fmaf(xr, w0[0], pi); pf = fmaf(xr, w0[1], pf);
                    pg = fmaf(xr, w0[2], pg); po = fmaf(xr, w0[3], po);
                }
                float ig = sigm_f(pi), fg = sigm_f(pf);
                float gg = tanh_f(pg), og = sigm_f(po);
                cc[r] = fmaf(fg, cc[r], ig * gg);
                wsl[woff[r]] = (_Float16)(og * tanh_f(cc[r]));
            }
            fast_barrier();   // h(t) visible for step t+1
        }

        if (L < 2) {
            // copy own chunk (already swizzled) -> global slot, then release flag
            const float4* sv = (const float4*)hown;
            float4* gdst = (float4*)gch;
#pragma unroll
            for (int k2 = 0; k2 < 8; ++k2) gdst[k2*NT + tid] = sv[k2*NT + tid];
            __threadfence();      // per-thread vmcnt drain + L2 writeback
            __syncthreads();
            if (tid == 0)
                __hip_atomic_store(fprod + s, 1, __ATOMIC_RELEASE,
                                   __HIP_MEMORY_SCOPE_AGENT);
        }
    }

    // ---- FC head (layer-2 blocks): hT = hown slice 15 (chunk 127) ----
    if (L == 2) {
        __syncthreads();
        for (int i = tid; i < NB*HDIM; i += NT) {
            int seq = i >> 7, uu = i & 127;
            hfin[seq][uu] = (float)hown[15*NB*HDIM + seq*HDIM + (uu ^ (8*(seq & 7)))];
        }
        __syncthreads();
        for (int d = tid; d < NB*64; d += NT) {
            int seq = d >> 6, un = d & 63;
            const float4* w4 = (const float4*)(fc1w + un*HDIM);
            const float4* h4 = (const float4*)hfin[seq];
            float sacc = fc1b[un];
#pragma unroll
            for (int k2 = 0; k2 < 32; ++k2) {
                float4 a = w4[k2], bb = h4[k2];
                sacc += a.x*bb.x + a.y*bb.y + a.z*bb.z + a.w*bb.w;
            }
            z_s[seq][un] = fmaxf(sacc, 0.0f);
        }
        __syncthreads();
        for (int d = tid; d < NB*5; d += NT) {
            int seq = d / 5, o = d - seq*5;
            const float* w = fc2w + o*64;
            float sacc = fc2b[o];
#pragma unroll
            for (int k2 = 0; k2 < 64; ++k2) sacc += w[k2] * z_s[seq][k2];
            out[(size_t)(g*NB + seq)*5 + o] = sacc;
        }
    }
}

extern "C" void kernel_launch(void* const* d_in, const int* in_sizes, int n_in,
                              void* d_out, int out_size, void* d_ws, size_t ws_size,
                              hipStream_t stream) {
    (void)in_sizes; (void)n_in; (void)out_size; (void)ws_size;
    const float* x    = (const float*)d_in[0];
    const float* Wih0 = (const float*)d_in[1];
    const float* Whh0 = (const float*)d_in[2];
    const float* bih0 = (const float*)d_in[3];
    const float* bhh0 = (const float*)d_in[4];
    const float* Wih1 = (const float*)d_in[5];
    const float* Whh1 = (const float*)d_in[6];
    const float* bih1 = (const float*)d_in[7];
    const float* bhh1 = (const float*)d_in[8];
    const float* Wih2 = (const float*)d_in[9];
    const float* Whh2 = (const float*)d_in[10];
    const float* bih2 = (const float*)d_in[11];
    const float* bhh2 = (const float*)d_in[12];
    const float* fc1w = (const float*)d_in[13];
    const float* fc1b = (const float*)d_in[14];
    const float* fc2w = (const float*)d_in[15];
    const float* fc2b = (const float*)d_in[16];
    float* out = (float*)d_out;

    _Float16* hbuf = (_Float16*)d_ws;                    // 128 MB chunk slots
    _Float16* wbuf = hbuf + (size_t)67108864;            // fp16 weights (640 KB)
    int* flags = (int*)(wbuf + (size_t)5*65536);         // 2*16*128 ints (16 KB)

    hipLaunchKernelGGL(convert_w, dim3(1280), dim3(256), 0, stream,
                       Whh0, Wih1, Whh1, Wih2, Whh2, wbuf, flags);
    hipLaunchKernelGGL(lstm3_pipe, dim3(3*NG), dim3(NT), 0, stream,
                       x, Wih0, bih0, bhh0, bih1, bhh1, bih2, bhh2,
                       fc1w, fc1b, fc2w, fc2b, out, hbuf, wbuf, flags);
}